// Round 1
// baseline (1126.797 us; speedup 1.0000x reference)
//
#include <hip/hip_runtime.h>

// GTEAST layer: N_SRC=100000, N_DST=50000, DEG=16, NODE_IN=128, EDGE_IN=64, HID=64
// Inputs: 0 node_features(100000x128) 1 edge_features(800000x64) 2 src_idx(800000)
//         3 We(64x64) 4 be(64) 5 Wa(64x64) 6 ba(64) 7 wa(64)
//         8 Wo(192x64) 9 bo(64) 10 Wn(192x64) 11 bn(64) 12 n_dst 13 deg
// Output: (50000x64) f32
//
// Key algebraic fold: a = leaky_relu(ef @ (Wa@wa) + ba.wa) -- kills a 6.6 GFLOP GEMM.
// h_neigh staged in d_out (same element count as final out); K2 rewrites in place.

#define XMW 200  // padded per-edge x row (192 used); 200 words => group rows hit distinct banks

__device__ __forceinline__ void sync_wave() {
  // wave-local LDS ordering: drain LDS ops + stop compiler reordering.
  asm volatile("s_waitcnt lgkmcnt(0)" ::: "memory");
}

__device__ __forceinline__ void copy_f4(float* dst, const float* src, int n4, int tid, int nthr) {
  for (int i = tid; i < n4; i += nthr)
    reinterpret_cast<float4*>(dst)[i] = reinterpret_cast<const float4*>(src)[i];
}

// ---------- K0: fold Wa@wa -> v[64], ba.wa -> vc[64] ----------
extern "C" __global__ void gteast_prep(const float* __restrict__ Wa,
                                       const float* __restrict__ ba,
                                       const float* __restrict__ wa,
                                       float* __restrict__ vc) {
  const int k = threadIdx.x;
  if (k < 64) {
    float s = 0.f;
    for (int h = 0; h < 64; ++h) s += Wa[k * 64 + h] * wa[h];
    vc[k] = s;
  }
  if (k == 0) {
    float c = 0.f;
    for (int h = 0; h < 64; ++h) c += ba[h] * wa[h];
    vc[64] = c;
  }
}

// ---------- K1: per-edge e_out + m, sparsemax, h_neigh ----------
// block=256 (4 waves), one dst per wave per iteration, 4 iterations.
// wave split: g=lane>>4 -> one of 4 edges per batch; t=lane&15 -> output feats 4t..4t+3.
extern "C" __global__ void __launch_bounds__(256, 2)
gteast_edge(const float* __restrict__ nf, const float* __restrict__ ef,
            const int* __restrict__ src_idx,
            const float* __restrict__ We, const float* __restrict__ be,
            const float* __restrict__ Wo, const float* __restrict__ bo,
            const float* __restrict__ vc,
            float* __restrict__ hn_out) {
  __shared__ __align__(16) float We_s[64 * 64];     // 16 KB
  __shared__ __align__(16) float Wo_s[192 * 64];    // 48 KB
  __shared__ __align__(16) float xm[4][4][XMW];     // 12.5 KB: per-wave, per-group x row
  __shared__ __align__(16) float v_s[64];
  __shared__ __align__(16) float be_s[64];
  __shared__ __align__(16) float bo_s[64];
  __shared__ float c_sh;

  const int tid = threadIdx.x;
  copy_f4(We_s, We, 64 * 64 / 4, tid, 256);
  copy_f4(Wo_s, Wo, 192 * 64 / 4, tid, 256);
  if (tid < 64) { v_s[tid] = vc[tid]; be_s[tid] = be[tid]; bo_s[tid] = bo[tid]; }
  if (tid == 0) c_sh = vc[64];
  __syncthreads();
  const float cval = c_sh;

  const int w = tid >> 6, lane = tid & 63, g = lane >> 4, t = lane & 15;
  float* xg = xm[w][g];
  const int wave_id = blockIdx.x * 4 + w;  // 0..12499

  for (int it = 0; it < 4; ++it) {
    const int n = wave_id + 12500 * it;  // uniform trip count: no divergent barriers
    float a_val[4];
    float4 mv[4];

    #pragma unroll
    for (int b = 0; b < 4; ++b) {
      const int e = n * 16 + 4 * b + g;
      // stage edge features for this group's edge
      float4 efv = *reinterpret_cast<const float4*>(ef + (long)e * 64 + 4 * t);
      *reinterpret_cast<float4*>(xg + 4 * t) = efv;
      sync_wave();

      // e_out = relu(ef @ We + be); also a_pre = ef . v
      float4 acc = *reinterpret_cast<const float4*>(be_s + 4 * t);
      float ap = 0.f;
      #pragma unroll 4
      for (int kk = 0; kk < 16; ++kk) {
        float4 x4 = *reinterpret_cast<const float4*>(xg + 4 * kk);
        float4 v4 = *reinterpret_cast<const float4*>(v_s + 4 * kk);
        ap += x4.x * v4.x; ap += x4.y * v4.y; ap += x4.z * v4.z; ap += x4.w * v4.w;
        const float xa[4] = {x4.x, x4.y, x4.z, x4.w};
        #pragma unroll
        for (int c = 0; c < 4; ++c) {
          float4 w4 = *reinterpret_cast<const float4*>(We_s + (4 * kk + c) * 64 + 4 * t);
          acc.x += w4.x * xa[c]; acc.y += w4.y * xa[c];
          acc.z += w4.z * xa[c]; acc.w += w4.w * xa[c];
        }
      }
      const float av = ap + cval;
      a_val[b] = av > 0.f ? av : 0.01f * av;  // leaky_relu slope 0.01
      float4 eo;
      eo.x = fmaxf(acc.x, 0.f); eo.y = fmaxf(acc.y, 0.f);
      eo.z = fmaxf(acc.z, 0.f); eo.w = fmaxf(acc.w, 0.f);

      sync_wave();  // all reads of xg[0..63] done before overwrite with h_src
      const int s = src_idx[e];
      float4 h0 = *reinterpret_cast<const float4*>(nf + (long)s * 128 + 4 * t);
      float4 h1 = *reinterpret_cast<const float4*>(nf + (long)s * 128 + 64 + 4 * t);
      *reinterpret_cast<float4*>(xg + 4 * t) = h0;
      *reinterpret_cast<float4*>(xg + 64 + 4 * t) = h1;
      *reinterpret_cast<float4*>(xg + 128 + 4 * t) = eo;
      sync_wave();

      // m = relu([h_src | e_out] @ Wo + bo)
      float4 macc = *reinterpret_cast<const float4*>(bo_s + 4 * t);
      #pragma unroll 4
      for (int kk = 0; kk < 48; ++kk) {
        float4 x4 = *reinterpret_cast<const float4*>(xg + 4 * kk);
        const float xa[4] = {x4.x, x4.y, x4.z, x4.w};
        #pragma unroll
        for (int c = 0; c < 4; ++c) {
          float4 w4 = *reinterpret_cast<const float4*>(Wo_s + (4 * kk + c) * 64 + 4 * t);
          macc.x += w4.x * xa[c]; macc.y += w4.y * xa[c];
          macc.z += w4.z * xa[c]; macc.w += w4.w * xa[c];
        }
      }
      mv[b].x = fmaxf(macc.x, 0.f); mv[b].y = fmaxf(macc.y, 0.f);
      mv[b].z = fmaxf(macc.z, 0.f); mv[b].w = fmaxf(macc.w, 0.f);
      sync_wave();  // m-phase reads complete before next batch's ef write
    }

    // gather all 16 attention logits into every lane (lanes of group g2 hold edge 4b+g2)
    float a_all[16];
    #pragma unroll
    for (int b2 = 0; b2 < 4; ++b2)
      #pragma unroll
      for (int g2 = 0; g2 < 4; ++g2)
        a_all[4 * b2 + g2] = __shfl(a_val[b2], g2 * 16);

    // sparsemax over 16 (identical data in every lane -> uniform control flow)
    float amax = a_all[0];
    #pragma unroll
    for (int d = 1; d < 16; ++d) amax = fmaxf(amax, a_all[d]);
    float zs[16];
    #pragma unroll
    for (int d = 0; d < 16; ++d) zs[d] = a_all[d] - amax;
    for (int i = 1; i < 16; ++i) {  // insertion sort, descending
      float key = zs[i]; int j = i - 1;
      while (j >= 0 && zs[j] < key) { zs[j + 1] = zs[j]; --j; }
      zs[j + 1] = key;
    }
    float cs = 0.f, ssum = 0.f; int km = 1;
    #pragma unroll
    for (int i = 0; i < 16; ++i) {
      cs += zs[i];
      if (1.f + (float)(i + 1) * zs[i] > cs) { km = i + 1; ssum += zs[i]; }
    }
    const float tau = (ssum - 1.f) / (float)km;

    // h_neigh = sum_d alpha_d * m_d  (own edges, then reduce across groups)
    float4 hn = {0.f, 0.f, 0.f, 0.f};
    #pragma unroll
    for (int b = 0; b < 4; ++b) {
      const float alpha = fmaxf(a_val[b] - amax - tau, 0.f);
      hn.x += alpha * mv[b].x; hn.y += alpha * mv[b].y;
      hn.z += alpha * mv[b].z; hn.w += alpha * mv[b].w;
    }
    hn.x += __shfl_xor(hn.x, 16); hn.y += __shfl_xor(hn.y, 16);
    hn.z += __shfl_xor(hn.z, 16); hn.w += __shfl_xor(hn.w, 16);
    hn.x += __shfl_xor(hn.x, 32); hn.y += __shfl_xor(hn.y, 32);
    hn.z += __shfl_xor(hn.z, 32); hn.w += __shfl_xor(hn.w, 32);
    if (g == 0)
      *reinterpret_cast<float4*>(hn_out + (long)n * 64 + 4 * t) = hn;
  }
}

// ---------- K2: out = relu([h_dst | h_neigh] @ Wn + bn), in place over d_out ----------
extern "C" __global__ void __launch_bounds__(256, 2)
gteast_out(const float* __restrict__ nf, const float* __restrict__ Wn,
           const float* __restrict__ bn, float* __restrict__ out) {
  __shared__ __align__(16) float Wn_s[192 * 64];
  __shared__ __align__(16) float xm[4][4][XMW];
  __shared__ __align__(16) float bn_s[64];

  const int tid = threadIdx.x;
  copy_f4(Wn_s, Wn, 192 * 64 / 4, tid, 256);
  if (tid < 64) bn_s[tid] = bn[tid];
  __syncthreads();

  const int w = tid >> 6, lane = tid & 63, g = lane >> 4, t = lane & 15;
  float* xg = xm[w][g];
  const int n = (blockIdx.x * 4 + w) * 4 + g;  // 0..49999

  float4 h0 = *reinterpret_cast<const float4*>(nf + (long)n * 128 + 4 * t);
  float4 h1 = *reinterpret_cast<const float4*>(nf + (long)n * 128 + 64 + 4 * t);
  float4 h2 = *reinterpret_cast<const float4*>(out + (long)n * 64 + 4 * t);  // h_neigh
  *reinterpret_cast<float4*>(xg + 4 * t) = h0;
  *reinterpret_cast<float4*>(xg + 64 + 4 * t) = h1;
  *reinterpret_cast<float4*>(xg + 128 + 4 * t) = h2;
  sync_wave();

  float4 acc = *reinterpret_cast<const float4*>(bn_s + 4 * t);
  #pragma unroll 4
  for (int kk = 0; kk < 48; ++kk) {
    float4 x4 = *reinterpret_cast<const float4*>(xg + 4 * kk);
    const float xa[4] = {x4.x, x4.y, x4.z, x4.w};
    #pragma unroll
    for (int c = 0; c < 4; ++c) {
      float4 w4 = *reinterpret_cast<const float4*>(Wn_s + (4 * kk + c) * 64 + 4 * t);
      acc.x += w4.x * xa[c]; acc.y += w4.y * xa[c];
      acc.z += w4.z * xa[c]; acc.w += w4.w * xa[c];
    }
  }
  acc.x = fmaxf(acc.x, 0.f); acc.y = fmaxf(acc.y, 0.f);
  acc.z = fmaxf(acc.z, 0.f); acc.w = fmaxf(acc.w, 0.f);
  *reinterpret_cast<float4*>(out + (long)n * 64 + 4 * t) = acc;
}

extern "C" void kernel_launch(void* const* d_in, const int* in_sizes, int n_in,
                              void* d_out, int out_size, void* d_ws, size_t ws_size,
                              hipStream_t stream) {
  const float* nf = (const float*)d_in[0];
  const float* ef = (const float*)d_in[1];
  const int* si   = (const int*)d_in[2];
  const float* We = (const float*)d_in[3];
  const float* be = (const float*)d_in[4];
  const float* Wa = (const float*)d_in[5];
  const float* ba = (const float*)d_in[6];
  const float* wa = (const float*)d_in[7];
  const float* Wo = (const float*)d_in[8];
  const float* bo = (const float*)d_in[9];
  const float* Wn = (const float*)d_in[10];
  const float* bn = (const float*)d_in[11];
  float* out = (float*)d_out;
  float* vc = (float*)d_ws;  // 65 floats

  gteast_prep<<<1, 64, 0, stream>>>(Wa, ba, wa, vc);
  gteast_edge<<<3125, 256, 0, stream>>>(nf, ef, si, We, be, Wo, bo, vc, out);
  gteast_out<<<3125, 256, 0, stream>>>(nf, Wn, bn, out);
}

// Round 2
// 418.542 us; speedup vs baseline: 2.6922x; 2.6922x over previous
//
#include <hip/hip_runtime.h>

// GTEAST layer, MFMA restructure.
// N_SRC=100000, N_DST=50000, DEG=16, NODE_IN=128, EDGE_IN=64, HID=64, E=800000
// Fold: a = leaky_relu(ef @ (Wa@wa) + ba.wa)  (fp32, exact)
// e_out / m / out GEMMs: bf16 v_mfma_f32_16x16x32_bf16, fp32 accum.
// Layout conventions (learn_hip m89/m97/m120 verified):
//   A-frag: lane q*16+t holds A[m=t][k=q*8+j], j=0..7 (8 bf16)
//   B-frag: lane q*16+t holds B^T[n=t][k=q*8+j]  (load from W^T rows)
//   C/D:    lane q*16+t holds C[row=q*4+reg][col=t]
// h_neigh staged fp32 in d_out; K2 rewrites in place.

#define ND 50000

typedef __bf16 bf16x8 __attribute__((ext_vector_type(8)));
typedef float f32x4 __attribute__((ext_vector_type(4)));

__device__ __forceinline__ void sync_wave() {
  asm volatile("s_waitcnt lgkmcnt(0)" ::: "memory");
}

// fp32 -> bf16 round-to-nearest-even (finite inputs)
__device__ __forceinline__ unsigned short f2bf(float x) {
  unsigned u = __float_as_uint(x);
  u += 0x7fffu + ((u >> 16) & 1u);
  return (unsigned short)(u >> 16);
}

union FragU { bf16x8 v; unsigned short u[8]; };

// load 8 consecutive floats at p, return bf16 frag; raw floats in fr[8]
__device__ __forceinline__ bf16x8 ld_cvt8(const float* __restrict__ p, float* fr) {
  float4 f0 = *reinterpret_cast<const float4*>(p);
  float4 f1 = *reinterpret_cast<const float4*>(p + 4);
  fr[0]=f0.x; fr[1]=f0.y; fr[2]=f0.z; fr[3]=f0.w;
  fr[4]=f1.x; fr[5]=f1.y; fr[6]=f1.z; fr[7]=f1.w;
  FragU fu;
  #pragma unroll
  for (int j = 0; j < 8; ++j) fu.u[j] = f2bf(fr[j]);
  return fu.v;
}

// ---------- K0: v = Wa@wa, c = ba.wa ----------
extern "C" __global__ void gteast_prep(const float* __restrict__ Wa,
                                       const float* __restrict__ ba,
                                       const float* __restrict__ wa,
                                       float* __restrict__ vc) {
  const int k = threadIdx.x;
  if (k < 64) {
    float s = 0.f;
    for (int h = 0; h < 64; ++h) s += Wa[k * 64 + h] * wa[h];
    vc[k] = s;
  }
  if (k == 0) {
    float c = 0.f;
    for (int h = 0; h < 64; ++h) c += ba[h] * wa[h];
    vc[64] = c;
  }
}

#define MFMA(a, b, c) __builtin_amdgcn_mfma_f32_16x16x32_bf16((a), (b), (c), 0, 0, 0)

// ---------- K1: fused e_out + attention + m + sparsemax + h_neigh ----------
// 4 waves/block, 1 dst per wave per iteration, 8 iterations.
extern "C" __global__ void __launch_bounds__(256, 2)
gteast_edge(const float* __restrict__ nf, const float* __restrict__ ef,
            const int* __restrict__ src_idx,
            const float* __restrict__ We, const float* __restrict__ be,
            const float* __restrict__ Wo, const float* __restrict__ bo,
            const float* __restrict__ vc,
            float* __restrict__ hn_out) {
  __shared__ unsigned short WeT[64 * 72];      // W^T[n][k], stride 72 (2-way banks, free)
  __shared__ unsigned short WoT[64 * 200];     // stride 200
  __shared__ unsigned short Elds[4][16 * 72];  // per-wave e_out tile [m][h]

  const int tid = threadIdx.x;
  for (int i = tid; i < 64 * 64; i += 256) {
    int k = i >> 6, n = i & 63;
    WeT[n * 72 + k] = f2bf(We[i]);
  }
  for (int i = tid; i < 192 * 64; i += 256) {
    int k = i >> 6, n = i & 63;
    WoT[n * 200 + k] = f2bf(Wo[i]);
  }
  __syncthreads();

  const int lane = tid & 63, w = tid >> 6;
  const int q = lane >> 4, t = lane & 15;

  // preload all B-frags to registers (We: 8, Wo: 24 -> 128 VGPRs)
  bf16x8 WeF[2][4], WoF[6][4];
  #pragma unroll
  for (int nt = 0; nt < 4; ++nt) {
    #pragma unroll
    for (int kc = 0; kc < 2; ++kc)
      WeF[kc][nt] = *reinterpret_cast<const bf16x8*>(&WeT[(nt * 16 + t) * 72 + kc * 32 + q * 8]);
    #pragma unroll
    for (int kc = 0; kc < 6; ++kc)
      WoF[kc][nt] = *reinterpret_cast<const bf16x8*>(&WoT[(nt * 16 + t) * 200 + kc * 32 + q * 8]);
  }
  // per-lane constants
  float vsl[16];
  #pragma unroll
  for (int kc = 0; kc < 2; ++kc)
    for (int j = 0; j < 8; ++j) vsl[kc * 8 + j] = vc[kc * 32 + q * 8 + j];
  const float cval = vc[64];
  float beL[4], boL[4];
  #pragma unroll
  for (int nt = 0; nt < 4; ++nt) { beL[nt] = be[nt * 16 + t]; boL[nt] = bo[nt * 16 + t]; }

  unsigned short* E = Elds[w];
  const int wid = blockIdx.x * 4 + w;  // 0..6251

  for (int it = 0; it < 8; ++it) {
    const int n = wid + it * 6252;
    if (n >= ND) continue;  // wave-uniform
    const long e0 = (long)n * 16;

    // --- ef A-frags (rows e0+t) + fp32 attention logit ---
    bf16x8 efr[2];
    float fr[8];
    float ap = 0.f;
    #pragma unroll
    for (int kc = 0; kc < 2; ++kc) {
      efr[kc] = ld_cvt8(ef + (e0 + t) * 64 + kc * 32 + q * 8, fr);
      #pragma unroll
      for (int j = 0; j < 8; ++j) ap += fr[j] * vsl[kc * 8 + j];
    }
    ap += __shfl_xor(ap, 16);
    ap += __shfl_xor(ap, 32);
    float a = ap + cval;
    a = a > 0.f ? a : 0.01f * a;  // leaky_relu, edge t's logit (replicated over quads)

    // --- e GEMM: e_out = relu(ef @ We + be) ---
    #pragma unroll
    for (int nt = 0; nt < 4; ++nt) {
      f32x4 c = {0.f, 0.f, 0.f, 0.f};
      c = MFMA(efr[0], WeF[0][nt], c);
      c = MFMA(efr[1], WeF[1][nt], c);
      #pragma unroll
      for (int r = 0; r < 4; ++r) {
        float vv = fmaxf(c[r] + beL[nt], 0.f);
        E[(4 * q + r) * 72 + nt * 16 + t] = f2bf(vv);  // row-major bf16 tile
      }
    }
    sync_wave();

    // --- m GEMM A-frags: gathered h_src (k=0..127) + e_out from LDS (k=128..191) ---
    const int s = src_idx[e0 + t];
    const float* hp = nf + (long)s * 128;
    bf16x8 af[6];
    #pragma unroll
    for (int kc = 0; kc < 4; ++kc) af[kc] = ld_cvt8(hp + kc * 32 + q * 8, fr);
    af[4] = *reinterpret_cast<const bf16x8*>(&E[t * 72 + q * 8]);
    af[5] = *reinterpret_cast<const bf16x8*>(&E[t * 72 + 32 + q * 8]);

    f32x4 accM[4];
    #pragma unroll
    for (int nt = 0; nt < 4; ++nt) {
      f32x4 c = {0.f, 0.f, 0.f, 0.f};
      #pragma unroll
      for (int kc = 0; kc < 6; ++kc) c = MFMA(af[kc], WoF[kc][nt], c);
      #pragma unroll
      for (int r = 0; r < 4; ++r) c[r] = fmaxf(c[r] + boL[nt], 0.f);
      accM[nt] = c;
    }
    sync_wave();  // E reads drained before next iteration overwrites

    // --- sparsemax over 16 logits (bitonic sort across lanes, desc) ---
    float z = a;
    #pragma unroll
    for (int k = 2; k <= 16; k <<= 1) {
      #pragma unroll
      for (int j = k >> 1; j > 0; j >>= 1) {
        float o = __shfl_xor(z, j);
        const bool upper = (t & j) != 0;
        const bool desc = (t & k) == 0;
        z = (upper != desc) ? fmaxf(z, o) : fminf(z, o);
      }
    }
    float cs = z;  // inclusive prefix sum over sorted
    #pragma unroll
    for (int off = 1; off < 16; off <<= 1) {
      float o = __shfl_up(cs, off, 16);
      cs += (t >= off) ? o : 0.f;
    }
    const bool gt = 1.f + (float)(t + 1) * z > cs;
    float kf = gt ? (float)(t + 1) : 0.f;
    float sv = gt ? z : 0.f;
    #pragma unroll
    for (int m = 1; m < 16; m <<= 1) {
      kf = fmaxf(kf, __shfl_xor(kf, m));
      sv += __shfl_xor(sv, m);
    }
    const float tau = (sv - 1.f) / kf;           // shift-invariant form
    const float alpha = fmaxf(a - tau, 0.f);     // own edge t

    // --- h_neigh = alpha^T . m  (rows 4q+r live in this lane's C regs) ---
    float al[4];
    #pragma unroll
    for (int r = 0; r < 4; ++r) al[r] = __shfl(alpha, 4 * q + r);
    float p[4];
    #pragma unroll
    for (int nt = 0; nt < 4; ++nt) {
      p[nt] = al[0] * accM[nt][0] + al[1] * accM[nt][1] +
              al[2] * accM[nt][2] + al[3] * accM[nt][3];
      p[nt] += __shfl_xor(p[nt], 16);
      p[nt] += __shfl_xor(p[nt], 32);
    }
    const float pown = (q == 0) ? p[0] : (q == 1) ? p[1] : (q == 2) ? p[2] : p[3];
    hn_out[(long)n * 64 + lane] = pown;  // coalesced 256B per wave
  }
}

// ---------- K2: out = relu([h_dst | h_neigh] @ Wn + bn), in place over d_out ----------
extern "C" __global__ void __launch_bounds__(256, 2)
gteast_out(const float* __restrict__ nf, const float* __restrict__ Wn,
           const float* __restrict__ bn, float* __restrict__ out) {
  __shared__ unsigned short WnT[64 * 200];
  const int tid = threadIdx.x;
  for (int i = tid; i < 192 * 64; i += 256) {
    int k = i >> 6, nn = i & 63;
    WnT[nn * 200 + k] = f2bf(Wn[i]);
  }
  __syncthreads();

  const int lane = tid & 63, w = tid >> 6, q = lane >> 4, t = lane & 15;
  bf16x8 WF[6][4];
  #pragma unroll
  for (int nt = 0; nt < 4; ++nt)
    #pragma unroll
    for (int kc = 0; kc < 6; ++kc)
      WF[kc][nt] = *reinterpret_cast<const bf16x8*>(&WnT[(nt * 16 + t) * 200 + kc * 32 + q * 8]);
  float bnL[4];
  #pragma unroll
  for (int nt = 0; nt < 4; ++nt) bnL[nt] = bn[nt * 16 + t];

  const int wid = blockIdx.x * 4 + w;  // 0..1563
  for (int it = 0; it < 2; ++it) {
    const int tile = wid + it * 1564;
    const int r0 = tile * 16;
    if (r0 >= ND) continue;

    float fr[8];
    bf16x8 af[6];
    const float* hp = nf + (long)(r0 + t) * 128;
    #pragma unroll
    for (int kc = 0; kc < 4; ++kc) af[kc] = ld_cvt8(hp + kc * 32 + q * 8, fr);
    const float* gp = out + (long)(r0 + t) * 64;  // h_neigh (staged by K1)
    #pragma unroll
    for (int kc = 0; kc < 2; ++kc) af[4 + kc] = ld_cvt8(gp + kc * 32 + q * 8, fr);

    #pragma unroll
    for (int nt = 0; nt < 4; ++nt) {
      f32x4 c = {0.f, 0.f, 0.f, 0.f};
      #pragma unroll
      for (int kc = 0; kc < 6; ++kc) c = MFMA(af[kc], WF[kc][nt], c);
      #pragma unroll
      for (int r = 0; r < 4; ++r)
        out[(long)(r0 + 4 * q + r) * 64 + nt * 16 + t] = fmaxf(c[r] + bnL[nt], 0.f);
    }
  }
}

extern "C" void kernel_launch(void* const* d_in, const int* in_sizes, int n_in,
                              void* d_out, int out_size, void* d_ws, size_t ws_size,
                              hipStream_t stream) {
  const float* nf = (const float*)d_in[0];
  const float* ef = (const float*)d_in[1];
  const int* si   = (const int*)d_in[2];
  const float* We = (const float*)d_in[3];
  const float* be = (const float*)d_in[4];
  const float* Wa = (const float*)d_in[5];
  const float* ba = (const float*)d_in[6];
  const float* wa = (const float*)d_in[7];
  const float* Wo = (const float*)d_in[8];
  const float* bo = (const float*)d_in[9];
  const float* Wn = (const float*)d_in[10];
  const float* bn = (const float*)d_in[11];
  float* out = (float*)d_out;
  float* vc = (float*)d_ws;  // 65 floats

  gteast_prep<<<1, 64, 0, stream>>>(Wa, ba, wa, vc);
  gteast_edge<<<1563, 256, 0, stream>>>(nf, ef, si, We, be, Wo, bo, vc, out);
  gteast_out<<<391, 256, 0, stream>>>(nf, Wn, bn, out);
}

// Round 3
// 387.506 us; speedup vs baseline: 2.9078x; 1.0801x over previous
//
#include <hip/hip_runtime.h>

// GTEAST layer, MFMA + latency-hiding restructure (round 3).
// N_SRC=100000, N_DST=50000, DEG=16, NODE_IN=128, EDGE_IN=64, HID=64, E=800000
// Fold: a = leaky_relu(ef @ (Wa@wa) + ba.wa)  (fp32, exact)
// GEMMs: bf16 v_mfma_f32_16x16x32_bf16, fp32 accum.
//   A-frag: lane q*16+t holds A[m=t][k=q*8+j]
//   B-frag: lane q*16+t holds B^T[n=t][k=q*8+j]  (from W^T rows in LDS)
//   C/D:    lane q*16+t holds C[row=q*4+reg][col=t]
// One wave = 8 consecutive dsts (128 consecutive edges): src_idx batched via
// 2 coalesced ints/lane + per-iter shuffle; ef prefetched 1 iter ahead; nf
// gather issued before m-GEMM. h_neigh staged fp32 in d_out; K2 in place.

#define ND 50000

typedef __bf16 bf16x8 __attribute__((ext_vector_type(8)));
typedef float f32x4 __attribute__((ext_vector_type(4)));

__device__ __forceinline__ void sync_wave() {
  asm volatile("s_waitcnt lgkmcnt(0)" ::: "memory");
}

// fp32 -> bf16 RNE (weights, one-time)
__device__ __forceinline__ unsigned short f2bf(float x) {
  unsigned u = __float_as_uint(x);
  u += 0x7fffu + ((u >> 16) & 1u);
  return (unsigned short)(u >> 16);
}

union Frag8 { bf16x8 v; unsigned u32[4]; };

// 8 floats -> bf16x8, round-half-up (+0x8000) + v_perm pack: ~1.5 VALU/elem
__device__ __forceinline__ bf16x8 pack8(const float* fr) {
  Frag8 f;
  #pragma unroll
  for (int j = 0; j < 4; ++j) {
    unsigned lo = __float_as_uint(fr[2 * j]) + 0x8000u;
    unsigned hi = __float_as_uint(fr[2 * j + 1]) + 0x8000u;
    f.u32[j] = __builtin_amdgcn_perm(hi, lo, 0x07060302);
  }
  return f.v;
}

#define MFMA(a, b, c) __builtin_amdgcn_mfma_f32_16x16x32_bf16((a), (b), (c), 0, 0, 0)

// ---------- K0: v = Wa@wa, c = ba.wa (256 threads, LDS reduce) ----------
extern "C" __global__ void gteast_prep(const float* __restrict__ Wa,
                                       const float* __restrict__ ba,
                                       const float* __restrict__ wa,
                                       float* __restrict__ vc) {
  __shared__ float red[260];
  const int tid = threadIdx.x, k = tid >> 2, p = tid & 3;
  float s = 0.f;
  for (int h = 16 * p; h < 16 * p + 16; ++h) s += Wa[k * 64 + h] * wa[h];
  red[tid] = s;
  if (tid < 4) {
    float sc = 0.f;
    for (int h = 16 * tid; h < 16 * tid + 16; ++h) sc += ba[h] * wa[h];
    red[256 + tid] = sc;
  }
  __syncthreads();
  if (p == 0) vc[k] = red[4 * k] + red[4 * k + 1] + red[4 * k + 2] + red[4 * k + 3];
  if (tid == 0) vc[64] = red[256] + red[257] + red[258] + red[259];
}

// ---------- K1: fused e_out + attention + m + sparsemax + h_neigh ----------
extern "C" __global__ void __launch_bounds__(256, 3)
gteast_edge(const float* __restrict__ nf, const float* __restrict__ ef,
            const int* __restrict__ src_idx,
            const float* __restrict__ We, const float* __restrict__ be,
            const float* __restrict__ Wo, const float* __restrict__ bo,
            const float* __restrict__ vc,
            float* __restrict__ hn_out) {
  __shared__ unsigned short WeT[64 * 72];      // W^T[n][k], stride 72 (16B-aligned rows)
  __shared__ unsigned short WoT[64 * 200];
  __shared__ unsigned short Elds[4][16 * 72];  // per-wave e_out tile [m][h]
  __shared__ float vls[68];                    // v[64], c at [64]

  const int tid = threadIdx.x;
  for (int i = tid; i < 64 * 64; i += 256) {
    int k = i >> 6, n = i & 63;
    WeT[n * 72 + k] = f2bf(We[i]);
  }
  for (int i = tid; i < 192 * 64; i += 256) {
    int k = i >> 6, n = i & 63;
    WoT[n * 200 + k] = f2bf(Wo[i]);
  }
  if (tid < 65) vls[tid] = vc[tid];
  __syncthreads();

  const int lane = tid & 63, w = tid >> 6;
  const int q = lane >> 4, t = lane & 15;
  const int wid = blockIdx.x * 4 + w;  // 0..6251; 6250 active
  if (wid * 8 >= ND) return;           // after the only __syncthreads

  unsigned short* E = Elds[w];
  const float cval = vls[64];
  float beL[4], boL[4];
  #pragma unroll
  for (int nt = 0; nt < 4; ++nt) { beL[nt] = be[nt * 16 + t]; boL[nt] = bo[nt * 16 + t]; }
  // logit vector slices (per-quad broadcast reads from LDS)
  float vsl[16];
  #pragma unroll
  for (int j = 0; j < 8; ++j) { vsl[j] = vls[q * 8 + j]; vsl[8 + j] = vls[32 + q * 8 + j]; }

  // batched src_idx: wave's 128 edges, 2 coalesced ints/lane
  const int si0 = src_idx[wid * 128 + lane];
  const int si1 = src_idx[wid * 128 + 64 + lane];

  const long ebase = (long)(wid * 128);

  // --- prologue: prefetch ef(it=0) and nf(it=0) ---
  float4 efn[4];
  {
    const float* er = ef + (ebase + t) * 64 + q * 8;
    efn[0] = *reinterpret_cast<const float4*>(er);
    efn[1] = *reinterpret_cast<const float4*>(er + 4);
    efn[2] = *reinterpret_cast<const float4*>(er + 32);
    efn[3] = *reinterpret_cast<const float4*>(er + 36);
  }
  float hraw[32];
  {
    const int s0 = __shfl(si0, t);
    const float* hp = nf + (long)s0 * 128 + q * 8;
    #pragma unroll
    for (int kc = 0; kc < 4; ++kc) {
      float4 a0 = *reinterpret_cast<const float4*>(hp + kc * 32);
      float4 a1 = *reinterpret_cast<const float4*>(hp + kc * 32 + 4);
      hraw[kc * 8 + 0] = a0.x; hraw[kc * 8 + 1] = a0.y; hraw[kc * 8 + 2] = a0.z; hraw[kc * 8 + 3] = a0.w;
      hraw[kc * 8 + 4] = a1.x; hraw[kc * 8 + 5] = a1.y; hraw[kc * 8 + 6] = a1.z; hraw[kc * 8 + 7] = a1.w;
    }
  }

  for (int it = 0; it < 8; ++it) {
    const int n = wid * 8 + it;
    const int itn = it < 7 ? it + 1 : 7;  // clamped prefetch index

    // --- snapshot current ef, issue next ef loads (full-iteration distance) ---
    float fe[16];
    fe[0] = efn[0].x; fe[1] = efn[0].y; fe[2] = efn[0].z; fe[3] = efn[0].w;
    fe[4] = efn[1].x; fe[5] = efn[1].y; fe[6] = efn[1].z; fe[7] = efn[1].w;
    fe[8] = efn[2].x; fe[9] = efn[2].y; fe[10] = efn[2].z; fe[11] = efn[2].w;
    fe[12] = efn[3].x; fe[13] = efn[3].y; fe[14] = efn[3].z; fe[15] = efn[3].w;
    {
      const float* er = ef + (ebase + itn * 16 + t) * 64 + q * 8;
      efn[0] = *reinterpret_cast<const float4*>(er);
      efn[1] = *reinterpret_cast<const float4*>(er + 4);
      efn[2] = *reinterpret_cast<const float4*>(er + 32);
      efn[3] = *reinterpret_cast<const float4*>(er + 36);
    }

    // --- fp32 attention logit (exact) ---
    float ap = 0.f;
    #pragma unroll
    for (int j = 0; j < 16; ++j) ap += fe[j] * vsl[j];
    ap += __shfl_xor(ap, 16);
    ap += __shfl_xor(ap, 32);
    float a = ap + cval;
    a = a > 0.f ? a : 0.01f * a;  // leaky_relu

    // --- e GEMM: e_out = relu(ef @ We + be) ---
    const bf16x8 e0 = pack8(fe), e1 = pack8(fe + 8);
    #pragma unroll
    for (int nt = 0; nt < 4; ++nt) {
      f32x4 c = {0.f, 0.f, 0.f, 0.f};
      c = MFMA(e0, *reinterpret_cast<const bf16x8*>(&WeT[(nt * 16 + t) * 72 + q * 8]), c);
      c = MFMA(e1, *reinterpret_cast<const bf16x8*>(&WeT[(nt * 16 + t) * 72 + 32 + q * 8]), c);
      #pragma unroll
      for (int r = 0; r < 4; ++r) {
        float vv = fmaxf(c[r] + beL[nt], 0.f);
        E[(4 * q + r) * 72 + nt * 16 + t] = f2bf(vv);
      }
    }
    sync_wave();

    // --- convert current nf gather -> A-frags (frees hraw) ---
    bf16x8 af[6];
    #pragma unroll
    for (int kc = 0; kc < 4; ++kc) af[kc] = pack8(hraw + kc * 8);
    af[4] = *reinterpret_cast<const bf16x8*>(&E[t * 72 + q * 8]);
    af[5] = *reinterpret_cast<const bf16x8*>(&E[t * 72 + 32 + q * 8]);

    // --- issue next iteration's nf gather (covered by m-GEMM + sparsemax) ---
    {
      const int sn = (itn < 4) ? __shfl(si0, 16 * itn + t)
                               : __shfl(si1, 16 * (itn - 4) + t);
      const float* hp = nf + (long)sn * 128 + q * 8;
      #pragma unroll
      for (int kc = 0; kc < 4; ++kc) {
        float4 a0 = *reinterpret_cast<const float4*>(hp + kc * 32);
        float4 a1 = *reinterpret_cast<const float4*>(hp + kc * 32 + 4);
        hraw[kc * 8 + 0] = a0.x; hraw[kc * 8 + 1] = a0.y; hraw[kc * 8 + 2] = a0.z; hraw[kc * 8 + 3] = a0.w;
        hraw[kc * 8 + 4] = a1.x; hraw[kc * 8 + 5] = a1.y; hraw[kc * 8 + 6] = a1.z; hraw[kc * 8 + 7] = a1.w;
      }
    }

    // --- m GEMM: m = relu([h_src | e_out] @ Wo + bo) ---
    f32x4 accM[4];
    #pragma unroll
    for (int nt = 0; nt < 4; ++nt) {
      f32x4 c = {0.f, 0.f, 0.f, 0.f};
      #pragma unroll
      for (int kc = 0; kc < 6; ++kc)
        c = MFMA(af[kc], *reinterpret_cast<const bf16x8*>(&WoT[(nt * 16 + t) * 200 + kc * 32 + q * 8]), c);
      #pragma unroll
      for (int r = 0; r < 4; ++r) c[r] = fmaxf(c[r] + boL[nt], 0.f);
      accM[nt] = c;
    }
    sync_wave();  // E reads drained before next iteration's writes

    // --- sparsemax over 16 logits (bitonic sort desc across t) ---
    float z = a;
    #pragma unroll
    for (int k = 2; k <= 16; k <<= 1) {
      #pragma unroll
      for (int j = k >> 1; j > 0; j >>= 1) {
        float o = __shfl_xor(z, j);
        const bool upper = (t & j) != 0;
        const bool desc = (t & k) == 0;
        z = (upper != desc) ? fmaxf(z, o) : fminf(z, o);
      }
    }
    float cs = z;
    #pragma unroll
    for (int off = 1; off < 16; off <<= 1) {
      float o = __shfl_up(cs, off, 16);
      cs += (t >= off) ? o : 0.f;
    }
    const bool gt = 1.f + (float)(t + 1) * z > cs;
    float kf = gt ? (float)(t + 1) : 0.f;
    float sv = gt ? z : 0.f;
    #pragma unroll
    for (int m = 1; m < 16; m <<= 1) {
      kf = fmaxf(kf, __shfl_xor(kf, m));
      sv += __shfl_xor(sv, m);
    }
    const float tau = (sv - 1.f) / kf;
    const float alpha = fmaxf(a - tau, 0.f);  // own edge t

    // --- h_neigh = alpha^T . m ---
    float al[4];
    #pragma unroll
    for (int r = 0; r < 4; ++r) al[r] = __shfl(alpha, 4 * q + r);
    float p[4];
    #pragma unroll
    for (int nt = 0; nt < 4; ++nt) {
      p[nt] = al[0] * accM[nt][0] + al[1] * accM[nt][1] +
              al[2] * accM[nt][2] + al[3] * accM[nt][3];
      p[nt] += __shfl_xor(p[nt], 16);
      p[nt] += __shfl_xor(p[nt], 32);
    }
    const float pown = (q == 0) ? p[0] : (q == 1) ? p[1] : (q == 2) ? p[2] : p[3];
    hn_out[(long)n * 64 + lane] = pown;  // coalesced 256B/wave
  }
}

// ---------- K2: out = relu([h_dst | h_neigh] @ Wn + bn), in place ----------
extern "C" __global__ void __launch_bounds__(256, 3)
gteast_out(const float* __restrict__ nf, const float* __restrict__ Wn,
           const float* __restrict__ bn, float* __restrict__ out) {
  __shared__ unsigned short WnT[64 * 200];
  const int tid = threadIdx.x;
  for (int i = tid; i < 192 * 64; i += 256) {
    int k = i >> 6, nn = i & 63;
    WnT[nn * 200 + k] = f2bf(Wn[i]);
  }
  __syncthreads();

  const int lane = tid & 63, w = tid >> 6, q = lane >> 4, t = lane & 15;
  const int tile = blockIdx.x * 4 + w;  // 0..3127; 3125 active
  if (tile >= ND / 16) return;
  const int r0 = tile * 16;

  float bnL[4];
  #pragma unroll
  for (int nt = 0; nt < 4; ++nt) bnL[nt] = bn[nt * 16 + t];

  float raw[8];
  bf16x8 af[6];
  const float* hp = nf + (long)(r0 + t) * 128 + q * 8;
  #pragma unroll
  for (int kc = 0; kc < 4; ++kc) {
    float4 a0 = *reinterpret_cast<const float4*>(hp + kc * 32);
    float4 a1 = *reinterpret_cast<const float4*>(hp + kc * 32 + 4);
    raw[0] = a0.x; raw[1] = a0.y; raw[2] = a0.z; raw[3] = a0.w;
    raw[4] = a1.x; raw[5] = a1.y; raw[6] = a1.z; raw[7] = a1.w;
    af[kc] = pack8(raw);
  }
  const float* gp = out + (long)(r0 + t) * 64 + q * 8;  // h_neigh staged by K1
  #pragma unroll
  for (int kc = 0; kc < 2; ++kc) {
    float4 a0 = *reinterpret_cast<const float4*>(gp + kc * 32);
    float4 a1 = *reinterpret_cast<const float4*>(gp + kc * 32 + 4);
    raw[0] = a0.x; raw[1] = a0.y; raw[2] = a0.z; raw[3] = a0.w;
    raw[4] = a1.x; raw[5] = a1.y; raw[6] = a1.z; raw[7] = a1.w;
    af[4 + kc] = pack8(raw);
  }

  #pragma unroll
  for (int nt = 0; nt < 4; ++nt) {
    f32x4 c = {0.f, 0.f, 0.f, 0.f};
    #pragma unroll
    for (int kc = 0; kc < 6; ++kc)
      c = MFMA(af[kc], *reinterpret_cast<const bf16x8*>(&WnT[(nt * 16 + t) * 200 + kc * 32 + q * 8]), c);
    #pragma unroll
    for (int r = 0; r < 4; ++r)
      out[(long)(r0 + 4 * q + r) * 64 + nt * 16 + t] = fmaxf(c[r] + bnL[nt], 0.f);
  }
}

extern "C" void kernel_launch(void* const* d_in, const int* in_sizes, int n_in,
                              void* d_out, int out_size, void* d_ws, size_t ws_size,
                              hipStream_t stream) {
  const float* nf = (const float*)d_in[0];
  const float* ef = (const float*)d_in[1];
  const int* si   = (const int*)d_in[2];
  const float* We = (const float*)d_in[3];
  const float* be = (const float*)d_in[4];
  const float* Wa = (const float*)d_in[5];
  const float* ba = (const float*)d_in[6];
  const float* wa = (const float*)d_in[7];
  const float* Wo = (const float*)d_in[8];
  const float* bo = (const float*)d_in[9];
  const float* Wn = (const float*)d_in[10];
  const float* bn = (const float*)d_in[11];
  float* out = (float*)d_out;
  float* vc = (float*)d_ws;  // 65 floats

  gteast_prep<<<1, 256, 0, stream>>>(Wa, ba, wa, vc);
  gteast_edge<<<1563, 256, 0, stream>>>(nf, ef, si, We, be, Wo, bo, vc, out);
  gteast_out<<<782, 256, 0, stream>>>(nf, Wn, bn, out);
}